// Round 7
// baseline (205.096 us; speedup 1.0000x reference)
//
#include <hip/hip_runtime.h>

// VectorQuantizer forward: out = codebook[argmin_k ||x - e_k||^2]
// inputs:  d_in[0] = inputs  [32,64,64,64] fp32  (N=131072 rows, D=64)
//          d_in[1] = embeddings [64,512] fp32    (D=64, K=512)
// out:     [32,64,64,64] fp32
//
// R7: split-bf16 MFMA, restructured from R6 per counters (all pipes <31%):
//  - RT=4 row-tiles/wave (64 rows) -> B L2 traffic halves (512->256 MB)
//  - two independent 3-MFMA chains per rt (8 chains in flight) + explicit
//    double-buffered B prefetch regs
//  - packed (score|k) argmin: scores shifted +64 (positive, one octave),
//    low 9 mantissa bits carry k; min/secondmin = 3x v_min/max_u32.
//    Quantization <= 3.9e-3 -> fallback tau = 0.008 (~1.4% rows take the
//    exact fp32 wave-parallel recompute; numpy first-min tie-break).

#define KC 512
#define DD 64
#define RT 4
#define TAU 0.008f

typedef __attribute__((ext_vector_type(8))) short short8;
typedef __attribute__((ext_vector_type(4))) float float4v;

__device__ inline unsigned short f2bf(float f) {   // RNE bf16
    unsigned u = __float_as_uint(f);
    return (unsigned short)((u + 0x7FFF + ((u >> 16) & 1)) >> 16);
}
__device__ inline float bf2f(unsigned short b) {
    return __uint_as_float((unsigned)b << 16);
}
__device__ inline unsigned umin_u(unsigned a, unsigned b) { return a < b ? a : b; }
__device__ inline unsigned umax_u(unsigned a, unsigned b) { return a > b ? a : b; }

// Per code-tile ct (16 codes): bias64 = 64 + ||e_k||^2 (fp32, sequential d),
// et (fp32 transposed codebook), Bh/Bl bf16 packs in 16x16x32 B-fragment
// order: element (lane l, j) = E[kc*32 + (l>>4)*8 + j][ct*16 + (l&15)].
// Layout verified by R6 passing.
__global__ __launch_bounds__(256) void vq_prep(const float* __restrict__ emb,
                                               float* __restrict__ et,
                                               float* __restrict__ bias64,
                                               short* __restrict__ Bh,
                                               short* __restrict__ Bl) {
    __shared__ float tile[DD][17];
    const int ct = blockIdx.x;            // 0..31
    const int t  = threadIdx.x;

    {   // stage emb[d][ct*16..+16] -> tile[d][c]
        const int d = t >> 2, c0 = (t & 3) * 4;
        float4 v = *(const float4*)(emb + (size_t)d * KC + ct * 16 + c0);
        tile[d][c0 + 0] = v.x; tile[d][c0 + 1] = v.y;
        tile[d][c0 + 2] = v.z; tile[d][c0 + 3] = v.w;
    }
    __syncthreads();

    if (t < 16) {   // bias64, exact sequential d-order, +64 shift for packing
        float s = 0.f;
        #pragma unroll
        for (int d = 0; d < DD; ++d) { float v = tile[d][t]; s += v * v; }
        bias64[ct * 16 + t] = s + 64.0f;
    }

    {   // et[(ct*16+c)][d0..d0+3]
        const int c = t >> 4, d0 = (t & 15) * 4;
        float4 v;
        v.x = tile[d0 + 0][c]; v.y = tile[d0 + 1][c];
        v.z = tile[d0 + 2][c]; v.w = tile[d0 + 3][c];
        *(float4*)(et + (size_t)(ct * 16 + c) * DD + d0) = v;
    }

    {   // B-fragment packs
        const int term = t >> 7;          // 0 = hi, 1 = lo
        const int kc   = (t >> 6) & 1;
        const int l    = t & 63;
        const int c    = l & 15, dq = l >> 4;
        short v8[8];
        #pragma unroll
        for (int j = 0; j < 8; ++j) {
            float f = tile[kc * 32 + dq * 8 + j][c];
            unsigned short h = f2bf(f);
            v8[j] = (short)(term == 0 ? h : f2bf(f - bf2f(h)));
        }
        short* dst = (term == 0 ? Bh : Bl) + ((size_t)(ct * 2 + kc) * 64 + l) * 8;
        *(short8*)dst = *(short8*)v8;
    }
}

__global__ __launch_bounds__(256, 2) void vq_main(const float* __restrict__ x_in,
                                                  const short* __restrict__ Bh,
                                                  const short* __restrict__ Bl,
                                                  const float* __restrict__ bias64,
                                                  const float* __restrict__ et,
                                                  float* __restrict__ out) {
    __shared__ float b64s[KC];
    __shared__ int   k1s[256];
    __shared__ float gaps[256];

    const int t = threadIdx.x, w = t >> 6, l = t & 63;
    const int col = l & 15, quad = l >> 4;
    const int R0 = blockIdx.x * 256;           // block covers 256 rows
    const int rowbase = R0 + w * 64;           // wave covers 64 rows

    {   // stage bias64 into LDS
        float2 b2 = *(const float2*)(bias64 + 2 * t);
        b64s[2 * t + 0] = b2.x; b64s[2 * t + 1] = b2.y;
    }

    // A fragments (16x16x32 A layout: m=lane&15, k=quad*8+j), rows split hi/lo.
    short8 ah[RT][2], al[RT][2];
    #pragma unroll
    for (int rt = 0; rt < RT; ++rt)
        #pragma unroll
        for (int kc = 0; kc < 2; ++kc) {
            const float* xp = x_in + (size_t)(rowbase + rt * 16 + col) * DD
                            + kc * 32 + quad * 8;
            float4 xa = *(const float4*)xp;
            float4 xb = *(const float4*)(xp + 4);
            float f[8] = {xa.x, xa.y, xa.z, xa.w, xb.x, xb.y, xb.z, xb.w};
            #pragma unroll
            for (int j = 0; j < 8; ++j) {
                unsigned short h = f2bf(f[j]);
                ah[rt][kc][j] = (short)h;
                al[rt][kc][j] = (short)f2bf(f[j] - bf2f(h));
            }
        }
    __syncthreads();

    unsigned v1[RT][4], v2[RT][4];
    #pragma unroll
    for (int rt = 0; rt < RT; ++rt)
        #pragma unroll
        for (int r = 0; r < 4; ++r) { v1[rt][r] = 0xFFFFFFFFu; v2[rt][r] = 0xFFFFFFFFu; }

    const short8* Bh8 = (const short8*)Bh;
    const short8* Bl8 = (const short8*)Bl;

    short8 bb[2][4];   // double-buffered B regs: {bh0, bh1, bl0, bl1}
    bb[0][0] = Bh8[(size_t)0 * 64 + l];
    bb[0][1] = Bh8[(size_t)1 * 64 + l];
    bb[0][2] = Bl8[(size_t)0 * 64 + l];
    bb[0][3] = Bl8[(size_t)1 * 64 + l];

    #pragma unroll 2
    for (int ct = 0; ct < 32; ++ct) {
        const int cur = ct & 1, nx = cur ^ 1;
        if (ct < 31) {   // prefetch next tile's B into the alternate buffer
            bb[nx][0] = Bh8[(size_t)((ct + 1) * 2 + 0) * 64 + l];
            bb[nx][1] = Bh8[(size_t)((ct + 1) * 2 + 1) * 64 + l];
            bb[nx][2] = Bl8[(size_t)((ct + 1) * 2 + 0) * 64 + l];
            bb[nx][3] = Bl8[(size_t)((ct + 1) * 2 + 1) * 64 + l];
        }
        const float    bs = b64s[ct * 16 + col];
        const unsigned kk = (unsigned)(ct * 16 + col);

        float4v c0[RT], c1[RT];
        #pragma unroll
        for (int rt = 0; rt < RT; ++rt) {   // 8 independent 3-chains
            float4v z = {0.f, 0.f, 0.f, 0.f};
            c0[rt] = __builtin_amdgcn_mfma_f32_16x16x32_bf16(ah[rt][0], bb[cur][0], z, 0, 0, 0);
            c1[rt] = __builtin_amdgcn_mfma_f32_16x16x32_bf16(ah[rt][1], bb[cur][1], z, 0, 0, 0);
        }
        #pragma unroll
        for (int rt = 0; rt < RT; ++rt) {
            c0[rt] = __builtin_amdgcn_mfma_f32_16x16x32_bf16(al[rt][0], bb[cur][0], c0[rt], 0, 0, 0);
            c1[rt] = __builtin_amdgcn_mfma_f32_16x16x32_bf16(al[rt][1], bb[cur][1], c1[rt], 0, 0, 0);
        }
        #pragma unroll
        for (int rt = 0; rt < RT; ++rt) {
            c0[rt] = __builtin_amdgcn_mfma_f32_16x16x32_bf16(ah[rt][0], bb[cur][2], c0[rt], 0, 0, 0);
            c1[rt] = __builtin_amdgcn_mfma_f32_16x16x32_bf16(ah[rt][1], bb[cur][3], c1[rt], 0, 0, 0);
        }
        #pragma unroll
        for (int rt = 0; rt < RT; ++rt) {
            #pragma unroll
            for (int r = 0; r < 4; ++r) {
                float s = fmaf(c0[rt][r] + c1[rt][r], -2.0f, bs);
                unsigned p = (__float_as_uint(s) & 0xFFFFFE00u) | kk;
                v2[rt][r] = umax_u(v1[rt][r], umin_u(v2[rt][r], p)); // old v1!
                v1[rt][r] = umin_u(v1[rt][r], p);
            }
        }
    }

    // Reduce (v1,v2) over the 16 col-lanes (C layout: row=quad*4+r, col=lane&15).
    #pragma unroll
    for (int rt = 0; rt < RT; ++rt)
        #pragma unroll
        for (int r = 0; r < 4; ++r) {
            unsigned a1 = v1[rt][r], a2 = v2[rt][r];
            #pragma unroll
            for (int m = 1; m <= 8; m <<= 1) {
                unsigned o1 = (unsigned)__shfl_xor((int)a1, m, 64);
                unsigned o2 = (unsigned)__shfl_xor((int)a2, m, 64);
                a2 = umin_u(umin_u(a2, o2), umax_u(a1, o1));
                a1 = umin_u(a1, o1);
            }
            if (col == 0) {
                const int row_l = w * 64 + rt * 16 + quad * 4 + r;
                k1s[row_l]  = (int)(a1 & 511u);
                float f1 = __uint_as_float(a1 & 0xFFFFFE00u);
                float f2 = __uint_as_float(a2 & 0xFFFFFE00u);
                gaps[row_l] = f2 - f1;
            }
        }

    // Exact fp32 fallback for near-tie rows (wave-uniform branch, ~1.4%).
    // Lane l scans codes [8l, 8l+8) ascending; cross-lane tie-break = lower k
    // => numpy first-min semantics, independent of the approx path.
    for (int rr = 0; rr < 64; ++rr) {
        const int row_l = w * 64 + rr;
        if (gaps[row_l] <= TAU) {
            const size_t grow = (size_t)(R0 + row_l) * DD;
            const int kbase = l * 8;
            float acc[8];
            #pragma unroll
            for (int j = 0; j < 8; ++j) acc[j] = 0.f;
            for (int d0 = 0; d0 < DD; d0 += 4) {
                float4 xv = *(const float4*)(x_in + grow + d0);
                #pragma unroll
                for (int j = 0; j < 8; ++j) {
                    float4 ev = *(const float4*)(et + (size_t)(kbase + j) * DD + d0);
                    acc[j] += xv.x * ev.x;
                    acc[j] += xv.y * ev.y;
                    acc[j] += xv.z * ev.z;
                    acc[j] += xv.w * ev.w;
                }
            }
            float4 b0 = *(const float4*)(bias64 + kbase);
            float4 b1 = *(const float4*)(bias64 + kbase + 4);
            float bbv[8] = {b0.x, b0.y, b0.z, b0.w, b1.x, b1.y, b1.z, b1.w};
            float bv = 3.4e38f; int bk = 0;
            #pragma unroll
            for (int j = 0; j < 8; ++j) {
                float s = bbv[j] - 2.f * acc[j];
                if (s < bv) { bv = s; bk = kbase + j; }
            }
            #pragma unroll
            for (int m = 1; m <= 32; m <<= 1) {
                float ov = __shfl_xor(bv, m, 64);
                int   ok = __shfl_xor(bk, m, 64);
                if (ov < bv || (ov == bv && ok < bk)) { bv = ov; bk = ok; }
            }
            if (l == 0) k1s[row_l] = bk;
        }
    }
    __syncthreads();

    // Gather epilogue: 4 sweeps; thread (r,seg) writes floats [seg*16,+16)
    // of row_l = i*64 + r. out = q (== x + (q-x) to ~5e-7; threshold 4.3e-3).
    {
        const int r = t >> 2, seg = t & 3;
        #pragma unroll
        for (int i = 0; i < 4; ++i) {
            const int row_l = i * 64 + r;
            const int bk = k1s[row_l];
            const float4* qp = (const float4*)(et + (size_t)bk * DD + seg * 16);
            float4* op = (float4*)(out + (size_t)(R0 + row_l) * DD + seg * 16);
            #pragma unroll
            for (int i4 = 0; i4 < 4; ++i4) op[i4] = qp[i4];
        }
    }
}

extern "C" void kernel_launch(void* const* d_in, const int* in_sizes, int n_in,
                              void* d_out, int out_size, void* d_ws, size_t ws_size,
                              hipStream_t stream) {
    const float* x_in = (const float*)d_in[0];   // [131072, 64]
    const float* emb  = (const float*)d_in[1];   // [64, 512]
    float* out = (float*)d_out;

    float* et     = (float*)d_ws;                     // 512*64 f32 = 131072 B
    float* bias64 = et + KC * DD;                     // 2048 B
    short* Bh     = (short*)(bias64 + KC);            // 64 KB
    short* Bl     = Bh + 32 * 2 * 64 * 8;             // 64 KB

    const int N = out_size / DD;                      // 131072 rows

    vq_prep<<<32, 256, 0, stream>>>(emb, et, bias64, Bh, Bl);
    vq_main<<<N / 256, 256, 0, stream>>>(x_in, Bh, Bl, bias64, et, out);
}

// Round 8
// 196.271 us; speedup vs baseline: 1.0450x; 1.0450x over previous
//
#include <hip/hip_runtime.h>

// VectorQuantizer forward: out = codebook[argmin_k ||x - e_k||^2]
// inputs:  d_in[0] = inputs  [32,64,64,64] fp32  (N=131072 rows, D=64)
//          d_in[1] = embeddings [64,512] fp32    (D=64, K=512)
// out:     [32,64,64,64] fp32
//
// R8: R6 parallelism (1024 blocks, RT=2, 32 rows/wave) + B staged through
//     LDS double-buffered (shared by 4 waves: B L2 traffic 512->128 MB, B-read
//     latency moves to the LDS pipe) + launch_bounds(256,4) for 4 blocks/CU.
//     R7 lesson: this kernel is latency-bound; never trade parallelism for
//     per-wave efficiency. Packed (score|k) argmin kept from R7 (validated).

#define KC 512
#define DD 64
#define RT 2
#define TAU 0.008f

typedef __attribute__((ext_vector_type(8))) short short8;
typedef __attribute__((ext_vector_type(4))) float float4v;

__device__ inline unsigned short f2bf(float f) {   // RNE bf16
    unsigned u = __float_as_uint(f);
    return (unsigned short)((u + 0x7FFF + ((u >> 16) & 1)) >> 16);
}
__device__ inline float bf2f(unsigned short b) {
    return __uint_as_float((unsigned)b << 16);
}
__device__ inline unsigned umin_u(unsigned a, unsigned b) { return a < b ? a : b; }
__device__ inline unsigned umax_u(unsigned a, unsigned b) { return a > b ? a : b; }

// Per code-tile ct (16 codes): bias64 = 64 + ||e_k||^2 (fp32, sequential d),
// et (fp32 transposed codebook), Bh/Bl bf16 packs in 16x16x32 B-fragment
// order: element (lane l, j) = E[kc*32 + (l>>4)*8 + j][ct*16 + (l&15)].
// Layout verified by R6/R7 passing.
__global__ __launch_bounds__(256) void vq_prep(const float* __restrict__ emb,
                                               float* __restrict__ et,
                                               float* __restrict__ bias64,
                                               short* __restrict__ Bh,
                                               short* __restrict__ Bl) {
    __shared__ float tile[DD][17];
    const int ct = blockIdx.x;            // 0..31
    const int t  = threadIdx.x;

    {   // stage emb[d][ct*16..+16] -> tile[d][c]
        const int d = t >> 2, c0 = (t & 3) * 4;
        float4 v = *(const float4*)(emb + (size_t)d * KC + ct * 16 + c0);
        tile[d][c0 + 0] = v.x; tile[d][c0 + 1] = v.y;
        tile[d][c0 + 2] = v.z; tile[d][c0 + 3] = v.w;
    }
    __syncthreads();

    if (t < 16) {   // bias64, exact sequential d-order, +64 shift for packing
        float s = 0.f;
        #pragma unroll
        for (int d = 0; d < DD; ++d) { float v = tile[d][t]; s += v * v; }
        bias64[ct * 16 + t] = s + 64.0f;
    }

    {   // et[(ct*16+c)][d0..d0+3]
        const int c = t >> 4, d0 = (t & 15) * 4;
        float4 v;
        v.x = tile[d0 + 0][c]; v.y = tile[d0 + 1][c];
        v.z = tile[d0 + 2][c]; v.w = tile[d0 + 3][c];
        *(float4*)(et + (size_t)(ct * 16 + c) * DD + d0) = v;
    }

    {   // B-fragment packs
        const int term = t >> 7;          // 0 = hi, 1 = lo
        const int kc   = (t >> 6) & 1;
        const int l    = t & 63;
        const int c    = l & 15, dq = l >> 4;
        short v8[8];
        #pragma unroll
        for (int j = 0; j < 8; ++j) {
            float f = tile[kc * 32 + dq * 8 + j][c];
            unsigned short h = f2bf(f);
            v8[j] = (short)(term == 0 ? h : f2bf(f - bf2f(h)));
        }
        short* dst = (term == 0 ? Bh : Bl) + ((size_t)(ct * 2 + kc) * 64 + l) * 8;
        *(short8*)dst = *(short8*)v8;
    }
}

__global__ __launch_bounds__(256, 4) void vq_main(const float* __restrict__ x_in,
                                                  const short* __restrict__ Bh,
                                                  const short* __restrict__ Bl,
                                                  const float* __restrict__ bias64,
                                                  const float* __restrict__ et,
                                                  float* __restrict__ out) {
    __shared__ float  b64s[KC];              // 2 KB
    __shared__ short8 bstage[2][4][64];      // 8 KB double-buffered B tiles
    __shared__ int    k1s[128];
    __shared__ float  gaps[128];

    const int t = threadIdx.x, w = t >> 6, l = t & 63;
    const int col = l & 15, quad = l >> 4;
    const int R0 = blockIdx.x * 128;         // block covers 128 rows
    const int rowbase = R0 + w * 32;         // wave covers 32 rows

    {   // stage bias64 into LDS (visible after first loop barrier)
        float2 b2 = *(const float2*)(bias64 + 2 * t);
        b64s[2 * t + 0] = b2.x; b64s[2 * t + 1] = b2.y;
    }

    // A fragments (16x16x32 A layout: m=lane&15, k=quad*8+j), rows split hi/lo.
    short8 ah[RT][2], al[RT][2];
    #pragma unroll
    for (int rt = 0; rt < RT; ++rt)
        #pragma unroll
        for (int kc = 0; kc < 2; ++kc) {
            const float* xp = x_in + (size_t)(rowbase + rt * 16 + col) * DD
                            + kc * 32 + quad * 8;
            float4 xa = *(const float4*)xp;
            float4 xb = *(const float4*)(xp + 4);
            float f[8] = {xa.x, xa.y, xa.z, xa.w, xb.x, xb.y, xb.z, xb.w};
            #pragma unroll
            for (int j = 0; j < 8; ++j) {
                unsigned short h = f2bf(f[j]);
                ah[rt][kc][j] = (short)h;
                al[rt][kc][j] = (short)f2bf(f[j] - bf2f(h));
            }
        }

    // Staging role: wave w stages fragment f=w of each tile.
    // f: 0=Bh/kc0, 1=Bh/kc1, 2=Bl/kc0, 3=Bl/kc1.
    const short* srcBase = (w < 2) ? Bh : Bl;
    const int    kcf     = w & 1;

    float4 preg = *(const float4*)(srcBase + ((size_t)(0 * 2 + kcf) * 64 + l) * 8);

    unsigned v1[RT][4], v2[RT][4];
    #pragma unroll
    for (int rt = 0; rt < RT; ++rt)
        #pragma unroll
        for (int r = 0; r < 4; ++r) { v1[rt][r] = 0xFFFFFFFFu; v2[rt][r] = 0xFFFFFFFFu; }

    #pragma unroll 2
    for (int ct = 0; ct < 32; ++ct) {
        const int cur = ct & 1;
        // commit prefetched tile to LDS, then one barrier per iteration.
        *(float4*)&bstage[cur][w][l] = preg;
        __syncthreads();
        if (ct < 31)   // prefetch next tile; latency hidden under compute
            preg = *(const float4*)(srcBase + ((size_t)((ct + 1) * 2 + kcf) * 64 + l) * 8);

        short8 bh0 = bstage[cur][0][l];
        short8 bh1 = bstage[cur][1][l];
        short8 bl0 = bstage[cur][2][l];
        short8 bl1 = bstage[cur][3][l];
        const float    bs = b64s[ct * 16 + col];
        const unsigned kk = (unsigned)(ct * 16 + col);

        float4v c0[RT], c1[RT];
        #pragma unroll
        for (int rt = 0; rt < RT; ++rt) {   // 4 independent 3-chains
            float4v z = {0.f, 0.f, 0.f, 0.f};
            c0[rt] = __builtin_amdgcn_mfma_f32_16x16x32_bf16(ah[rt][0], bh0, z, 0, 0, 0);
            c1[rt] = __builtin_amdgcn_mfma_f32_16x16x32_bf16(ah[rt][1], bh1, z, 0, 0, 0);
        }
        #pragma unroll
        for (int rt = 0; rt < RT; ++rt) {
            c0[rt] = __builtin_amdgcn_mfma_f32_16x16x32_bf16(al[rt][0], bh0, c0[rt], 0, 0, 0);
            c1[rt] = __builtin_amdgcn_mfma_f32_16x16x32_bf16(al[rt][1], bh1, c1[rt], 0, 0, 0);
        }
        #pragma unroll
        for (int rt = 0; rt < RT; ++rt) {
            c0[rt] = __builtin_amdgcn_mfma_f32_16x16x32_bf16(ah[rt][0], bl0, c0[rt], 0, 0, 0);
            c1[rt] = __builtin_amdgcn_mfma_f32_16x16x32_bf16(ah[rt][1], bl1, c1[rt], 0, 0, 0);
        }
        #pragma unroll
        for (int rt = 0; rt < RT; ++rt) {
            #pragma unroll
            for (int r = 0; r < 4; ++r) {
                float s = fmaf(c0[rt][r] + c1[rt][r], -2.0f, bs);
                unsigned p = (__float_as_uint(s) & 0xFFFFFE00u) | kk;  // v_and_or
                v2[rt][r] = umax_u(v1[rt][r], umin_u(v2[rt][r], p));   // old v1!
                v1[rt][r] = umin_u(v1[rt][r], p);
            }
        }
    }

    // Reduce (v1,v2) over the 16 col-lanes (C layout: row=quad*4+r, col=lane&15).
    #pragma unroll
    for (int rt = 0; rt < RT; ++rt)
        #pragma unroll
        for (int r = 0; r < 4; ++r) {
            unsigned a1 = v1[rt][r], a2 = v2[rt][r];
            #pragma unroll
            for (int m = 1; m <= 8; m <<= 1) {
                unsigned o1 = (unsigned)__shfl_xor((int)a1, m, 64);
                unsigned o2 = (unsigned)__shfl_xor((int)a2, m, 64);
                a2 = umin_u(umin_u(a2, o2), umax_u(a1, o1));
                a1 = umin_u(a1, o1);
            }
            if (col == 0) {
                const int row_l = w * 32 + rt * 16 + quad * 4 + r;
                k1s[row_l]  = (int)(a1 & 511u);
                float f1 = __uint_as_float(a1 & 0xFFFFFE00u);
                float f2 = __uint_as_float(a2 & 0xFFFFFE00u);
                gaps[row_l] = f2 - f1;
            }
        }

    // Exact fp32 fallback for near-tie rows (wave-uniform branch, ~1-2%).
    // Lane l scans codes [8l, 8l+8) ascending; cross-lane tie-break = lower k
    // => numpy first-min semantics, independent of the approx path.
    for (int rr = 0; rr < 32; ++rr) {
        const int row_l = w * 32 + rr;
        if (gaps[row_l] <= TAU) {
            const size_t grow = (size_t)(R0 + row_l) * DD;
            const int kbase = l * 8;
            float acc[8];
            #pragma unroll
            for (int j = 0; j < 8; ++j) acc[j] = 0.f;
            for (int d0 = 0; d0 < DD; d0 += 4) {
                float4 xv = *(const float4*)(x_in + grow + d0);
                #pragma unroll
                for (int j = 0; j < 8; ++j) {
                    float4 ev = *(const float4*)(et + (size_t)(kbase + j) * DD + d0);
                    acc[j] += xv.x * ev.x;
                    acc[j] += xv.y * ev.y;
                    acc[j] += xv.z * ev.z;
                    acc[j] += xv.w * ev.w;
                }
            }
            float4 b0 = *(const float4*)(bias64 + kbase);
            float4 b1 = *(const float4*)(bias64 + kbase + 4);
            float bbv[8] = {b0.x, b0.y, b0.z, b0.w, b1.x, b1.y, b1.z, b1.w};
            float bv = 3.4e38f; int bk = 0;
            #pragma unroll
            for (int j = 0; j < 8; ++j) {
                float s = bbv[j] - 2.f * acc[j];
                if (s < bv) { bv = s; bk = kbase + j; }
            }
            #pragma unroll
            for (int m = 1; m <= 32; m <<= 1) {
                float ov = __shfl_xor(bv, m, 64);
                int   ok = __shfl_xor(bk, m, 64);
                if (ov < bv || (ov == bv && ok < bk)) { bv = ov; bk = ok; }
            }
            if (l == 0) k1s[row_l] = bk;
        }
    }
    __syncthreads();

    // Gather epilogue: thread t writes half a row (32 floats). out = q
    // (== x + (q-x) to ~5e-7 in fp32; threshold is 4.3e-3).
    {
        const int row_l = t >> 1, half = t & 1;
        const int bk = k1s[row_l];
        const float4* qp = (const float4*)(et + (size_t)bk * DD + half * 32);
        float4* op = (float4*)(out + (size_t)(R0 + row_l) * DD + half * 32);
        #pragma unroll
        for (int i = 0; i < 8; ++i) op[i] = qp[i];
    }
}

extern "C" void kernel_launch(void* const* d_in, const int* in_sizes, int n_in,
                              void* d_out, int out_size, void* d_ws, size_t ws_size,
                              hipStream_t stream) {
    const float* x_in = (const float*)d_in[0];   // [131072, 64]
    const float* emb  = (const float*)d_in[1];   // [64, 512]
    float* out = (float*)d_out;

    float* et     = (float*)d_ws;                     // 512*64 f32 = 131072 B
    float* bias64 = et + KC * DD;                     // 2048 B
    short* Bh     = (short*)(bias64 + KC);            // 64 KB
    short* Bl     = Bh + 32 * 2 * 64 * 8;             // 64 KB

    const int N = out_size / DD;                      // 131072 rows

    vq_prep<<<32, 256, 0, stream>>>(emb, et, bias64, Bh, Bl);
    vq_main<<<N / 128, 256, 0, stream>>>(x_in, Bh, Bl, bias64, et, out);
}